// Round 7
// baseline (151820.081 us; speedup 1.0000x reference)
//
#include <hip/hip_runtime.h>

#define B_  64
#define T_  2048
#define I_  128
#define H_  256
#define G4  1024   // 4*H
#define TC  128    // timestep chunk

typedef float    f32x4 __attribute__((ext_vector_type(4)));
typedef _Float16 f16x8 __attribute__((ext_vector_type(8)));
typedef _Float16 f16x2 __attribute__((ext_vector_type(2)));

__device__ __forceinline__ float dot2f(unsigned w, unsigned h, float acc) {
#if __has_builtin(__builtin_amdgcn_fdot2)
  return __builtin_amdgcn_fdot2(__builtin_bit_cast(f16x2, w),
                                __builtin_bit_cast(f16x2, h), acc, false);
#else
  f16x2 a = __builtin_bit_cast(f16x2, w), b = __builtin_bit_cast(f16x2, h);
  return acc + (float)a[0] * (float)b[0] + (float)a[1] * (float)b[1];
#endif
}

__device__ __forceinline__ unsigned short h16bits(float f) {
  return __builtin_bit_cast(unsigned short, (_Float16)f);
}
__device__ __forceinline__ float sigm(float x) { return 1.f / (1.f + __expf(-x)); }
__device__ __forceinline__ float tanh_fast(float x) { return 2.f / (1.f + __expf(-2.f * x)) - 1.f; }

// ---------------- prep kernels ----------------

// W_hh [1024][256] f32 -> packed f16x2 dwords: wall[kq][row] uint4,
// kq in [0,32): uint4 kq covers h-dims 8*kq .. 8*kq+7.
__global__ void prep_w(const float* __restrict__ Whh, uint4* __restrict__ wall) {
  int idx = blockIdx.x * 256 + threadIdx.x;   // 0..32767
  if (idx >= 32 * 1024) return;
  int c4 = idx >> 10, r = idx & 1023;
  unsigned q[4];
#pragma unroll
  for (int m = 0; m < 4; m++) {
    int kd = 4 * c4 + m;
    unsigned lo = h16bits(Whh[r * 256 + 2 * kd]);
    unsigned hi = h16bits(Whh[r * 256 + 2 * kd + 1]);
    q[m] = lo | (hi << 16);
  }
  wall[c4 * 1024 + r] = make_uint4(q[0], q[1], q[2], q[3]);
}

__global__ void prep_f16(const float* __restrict__ src, _Float16* __restrict__ dst, int n) {
  int i = blockIdx.x * 256 + threadIdx.x;
  if (i < n) dst[i] = (_Float16)src[i];
}

__global__ void prep_bias(const float* __restrict__ bi, const float* __restrict__ bh,
                          float* __restrict__ bias) {
  int i = blockIdx.x * 256 + threadIdx.x;
  if (i < G4) bias[i] = bi[i] + bh[i];
}

// ---------------- projection GEMM (f16 MFMA) ----------------
template <int K, bool SRC_F32>
__global__ __launch_bounds__(256) void proj_kernel(const void* __restrict__ Asrc,
                                                   const _Float16* __restrict__ Wf,
                                                   const float* __restrict__ bias,
                                                   float* __restrict__ xw, int t0) {
  const int m  = blockIdx.x;
  const int n0 = blockIdx.y * 64;
  const int tid = threadIdx.x;
  const int lane = tid & 63, wv = tid >> 6;

  __shared__ _Float16 As[64][40];
  __shared__ _Float16 Bs[64][40];

  f32x4 acc[4] = {f32x4{0,0,0,0}, f32x4{0,0,0,0}, f32x4{0,0,0,0}, f32x4{0,0,0,0}};

  const int r  = tid >> 2;
  const int kq = (tid & 3) * 8;
  const int r_g = m * 64 + r;
  const int b  = r_g >> 7;          // TC = 128
  const int tc = r_g & (TC - 1);
  long arow;
  if (SRC_F32) arow = (long)(b * T_ + t0 + tc) * K;
  else         arow = (long)r_g * K;

  for (int k0 = 0; k0 < K; k0 += 32) {
    if (SRC_F32) {
      const float* ap = (const float*)Asrc + arow + k0 + kq;
      float4 a0 = *(const float4*)ap;
      float4 a1 = *(const float4*)(ap + 4);
      _Float16* d = &As[r][kq];
      d[0] = (_Float16)a0.x; d[1] = (_Float16)a0.y; d[2] = (_Float16)a0.z; d[3] = (_Float16)a0.w;
      d[4] = (_Float16)a1.x; d[5] = (_Float16)a1.y; d[6] = (_Float16)a1.z; d[7] = (_Float16)a1.w;
    } else {
      const _Float16* ap = (const _Float16*)Asrc + arow + k0 + kq;
      *(uint4*)&As[r][kq] = *(const uint4*)ap;
    }
    *(uint4*)&Bs[r][kq] = *(const uint4*)(Wf + (long)(n0 + r) * K + k0 + kq);
    __syncthreads();

    f16x8 av = *(const f16x8*)&As[wv * 16 + (lane & 15)][(lane >> 4) * 8];
#pragma unroll
    for (int q = 0; q < 4; q++) {
      f16x8 bv = *(const f16x8*)&Bs[q * 16 + (lane & 15)][(lane >> 4) * 8];
      acc[q] = __builtin_amdgcn_mfma_f32_16x16x32_f16(av, bv, acc[q], 0, 0, 0);
    }
    __syncthreads();
  }

  const int row_in = wv * 16 + ((lane >> 4) << 2);
  const int col_in = lane & 15;
#pragma unroll
  for (int q = 0; q < 4; q++) {
#pragma unroll
    for (int i = 0; i < 4; i++) {
      int rr = m * 64 + row_in + i;
      int cc = n0 + q * 16 + col_in;
      xw[(long)rr * G4 + cc] = acc[q][i] + bias[cc];
    }
  }
}

// ---------------- recurrent scan: 4 blocks per batch ----------------
// Block (b,q): owns gate rows G = g*256 + q*64 + u (g=0..3, u=0..63) -> all
// four gates for h-indices jj = q*64+u, so the c/h update is block-local.
// Per-thread W = 16 uint4 = 64 dwords (512 thr x 64 = the full 128 KB slice)
// -> ~110 VGPR total, actually register-resident (rounds 2-6 needed 192-384
// dwords/thread, which exceeds the 256-ArchVGPR file; this fits).
// Per step: blocks exchange their 64 h values (f16) via global memory with
// device-scope release/acquire flags; hxg double-buffered by step parity.
// Grid = 256 blocks; the LDS pad forces 1 block/CU -> all blocks co-resident.

#define W16(X) X(0) X(1) X(2) X(3) X(4) X(5) X(6) X(7) \
               X(8) X(9) X(10) X(11) X(12) X(13) X(14) X(15)

#define LOADW(i) uint4 w_##i = wall[(2 * (i) + half) * 1024 + G];
#define PINW(i)  asm volatile("" : "+v"(w_##i.x), "+v"(w_##i.y), "+v"(w_##i.z), "+v"(w_##i.w));
#define DOTW(i)  { uint4 hv = hs4[2 * (i) + half]; \
  aa = dot2f(w_##i.x, hv.x, aa); ab = dot2f(w_##i.y, hv.y, ab); \
  aa = dot2f(w_##i.z, hv.z, aa); ab = dot2f(w_##i.w, hv.w, ab); }

__global__ __launch_bounds__(512, 1) void scan_kernel(
    const float* __restrict__ xw,      // [B*TC][1024] chunk
    const uint4* __restrict__ wall,    // [32][1024]
    const float* __restrict__ mask,    // [B][256]
    float* __restrict__ hstate, float* __restrict__ cstate,  // [B][256]
    _Float16* __restrict__ ychunk,     // layer0 out chunk (or null)
    float* __restrict__ out,           // layer1: d_out base (or null)
    float* __restrict__ hn, float* __restrict__ cn,          // last chunk only
    unsigned short* __restrict__ hxg,  // [2 parity][B][256] f16 exchange
    int* __restrict__ flags,           // [B][4], monotonic per layer
    int t0) {
  const int blk = blockIdx.x;
  const int b = blk >> 2, q = blk & 3;
  const int t = threadIdx.x;
  const int r = t & 255, half = t >> 8;
  const int g = r >> 6, u = r & 63;
  const int G = g * 256 + q * 64 + u;   // global gate row
  const int jj = q * 64 + u;            // own h index (valid for t<64: g==0)

  __shared__ unsigned short hsm[256];   // h (f16) for current step's dots
  __shared__ float pl[512];             // half-partial exchange
  __shared__ float act[256];            // gate activations
  __shared__ char pad_lds[84 << 10];    // force 1 block/CU (co-residency)
  if ((unsigned long)xw == 0) { pad_lds[t] = 1; out[0] = pad_lds[t + 1]; }

  // W slice into 16 named uint4 (64 dwords), pinned
  W16(LOADW)
  W16(PINW)

  float c_reg = 0.f, h_reg = 0.f, mk = 0.f;
  if (t < 64) {
    c_reg = cstate[b * 256 + jj];
    mk    = mask[b * 256 + jj];
  }
  if (t < 128) {
    float h0v = hstate[b * 256 + 2 * t];
    float h1v = hstate[b * 256 + 2 * t + 1];
    ((unsigned*)hsm)[t] = (unsigned)h16bits(h0v) | ((unsigned)h16bits(h1v) << 16);
  }
  __syncthreads();

  const uint4* hs4 = (const uint4*)hsm;
  const float* xwb = xw + (long)b * TC * G4;
  int* flg = flags + b * 4;

  float xcur = (half == 0) ? xwb[G] : 0.f;

  for (int tc = 0; tc < TC; ++tc) {
    // prefetch next step's xw (hidden under this step's work)
    float xnext = 0.f;
    if (half == 0 && tc + 1 < TC) xnext = xwb[(long)(tc + 1) * G4 + G];

    if (tc > 0) {
      const int target = t0 + tc;
      if (t < 3) {
        const int qq = (t >= q) ? t + 1 : t;   // the 3 other slices
        while (__hip_atomic_load(&flg[qq], __ATOMIC_ACQUIRE,
                                 __HIP_MEMORY_SCOPE_AGENT) < target)
          __builtin_amdgcn_s_sleep(1);
      }
      __syncthreads();
      if (t < 128)
        ((unsigned*)hsm)[t] =
            ((const unsigned*)(hxg + ((tc - 1) & 1) * (B_ * 256)))[b * 128 + t];
      __syncthreads();
    }

    float aa = xcur, ab = 0.f;
    W16(DOTW)
    pl[t] = aa + ab;
    __syncthreads();

    if (t < 256) {
      float av = pl[t] + pl[t + 256];
      act[t] = (g == 2) ? tanh_fast(av) : sigm(av);
    }
    __syncthreads();

    if (t < 64) {
      float ci = act[t], cf = act[64 + t], cg = act[128 + t], co = act[192 + t];
      c_reg = cf * c_reg + ci * cg;
      h_reg = co * tanh_fast(c_reg);
      float hm = h_reg * mk;
      if (ychunk) ychunk[(b * TC + tc) * H_ + jj] = (_Float16)hm;
      else        out[(long)(b * T_ + t0 + tc) * H_ + jj] = hm;
      if (tc + 1 < TC)
        hxg[(tc & 1) * (B_ * 256) + b * 256 + jj] = h16bits(h_reg);
    }

    if (tc + 1 < TC) {
      __threadfence();     // each wave drains its stores to device scope
      __syncthreads();
      if (t == 0)
        __hip_atomic_store(&flg[q], t0 + tc + 1, __ATOMIC_RELEASE,
                           __HIP_MEMORY_SCOPE_AGENT);
    }
    xcur = xnext;
  }

  if (t < 64) {
    hstate[b * 256 + jj] = h_reg;
    cstate[b * 256 + jj] = c_reg;
    if (hn) { hn[b * 256 + jj] = h_reg; cn[b * 256 + jj] = c_reg; }
  }
}

// ---------------- host launch ----------------
extern "C" void kernel_launch(void* const* d_in, const int* in_sizes, int n_in,
                              void* d_out, int out_size, void* d_ws, size_t ws_size,
                              hipStream_t stream) {
  const float* x     = (const float*)d_in[0];
  const float* Wih0  = (const float*)d_in[1];
  const float* Whh0  = (const float*)d_in[2];
  const float* bih0  = (const float*)d_in[3];
  const float* bhh0  = (const float*)d_in[4];
  const float* mask0 = (const float*)d_in[5];
  const float* Wih1  = (const float*)d_in[6];
  const float* Whh1  = (const float*)d_in[7];
  const float* bih1  = (const float*)d_in[8];
  const float* bhh1  = (const float*)d_in[9];
  const float* mask1 = (const float*)d_in[10];

  float* out = (float*)d_out;
  float* hn  = out + (long)B_ * T_ * H_;   // [2][64][256]
  float* cn  = hn + 2 * B_ * H_;

  char* w = (char*)d_ws;
  uint4*    wall0  = (uint4*)w;      w += 512 << 10;   // [32][1024] uint4
  uint4*    wall1  = (uint4*)w;      w += 512 << 10;
  _Float16* wf0    = (_Float16*)w;   w += 256 << 10;   // [1024][128]
  _Float16* wf1    = (_Float16*)w;   w += 512 << 10;   // [1024][256]
  float*    bias0  = (float*)w;      w += 4 << 10;
  float*    bias1  = (float*)w;      w += 4 << 10;
  float*    h0s    = (float*)w;      w += 64 << 10;
  float*    c0s    = (float*)w;      w += 64 << 10;
  float*    h1s    = (float*)w;      w += 64 << 10;
  float*    c1s    = (float*)w;      w += 64 << 10;
  unsigned short* hxg = (unsigned short*)w; w += 64 << 10;  // [2][64][256] f16
  int*      flags0 = (int*)w;        w += 1 << 10;     // [64][4]
  int*      flags1 = (int*)w;        w += 1 << 10;
  float*    xwbuf  = (float*)w;      w += (long)B_ * TC * G4 * 4;   // 32 MB
  _Float16* ybuf   = (_Float16*)w;   w += (long)B_ * TC * H_ * 2;   // 4 MB

  // zero h/c states (contiguous 256KB) and flags (2KB, contiguous after hxg)
  hipMemsetAsync(h0s, 0, 4 * (64 << 10), stream);
  hipMemsetAsync(flags0, 0, 2 << 10, stream);

  // weight prep
  prep_w<<<128, 256, 0, stream>>>(Whh0, wall0);
  prep_w<<<128, 256, 0, stream>>>(Whh1, wall1);
  prep_f16<<<512, 256, 0, stream>>>(Wih0, wf0, G4 * I_);
  prep_f16<<<1024, 256, 0, stream>>>(Wih1, wf1, G4 * H_);
  prep_bias<<<4, 256, 0, stream>>>(bih0, bhh0, bias0);
  prep_bias<<<4, 256, 0, stream>>>(bih1, bhh1, bias1);

  const int nchunk = T_ / TC;  // 16
  for (int k = 0; k < nchunk; k++) {
    int t0 = k * TC;
    bool last = (k == nchunk - 1);
    proj_kernel<I_, true><<<dim3(B_ * TC / 64, G4 / 64), 256, 0, stream>>>(
        x, wf0, bias0, xwbuf, t0);
    scan_kernel<<<B_ * 4, 512, 0, stream>>>(xwbuf, wall0, mask0, h0s, c0s,
                                            ybuf, nullptr,
                                            last ? hn : nullptr, last ? cn : nullptr,
                                            hxg, flags0, t0);
    proj_kernel<H_, false><<<dim3(B_ * TC / 64, G4 / 64), 256, 0, stream>>>(
        ybuf, wf1, bias1, xwbuf, t0);
    scan_kernel<<<B_ * 4, 512, 0, stream>>>(xwbuf, wall1, mask1, h1s, c1s,
                                            nullptr, out,
                                            last ? hn + B_ * H_ : nullptr,
                                            last ? cn + B_ * H_ : nullptr,
                                            hxg, flags1, t0);
  }
}

// Round 8
// 6371.899 us; speedup vs baseline: 23.8265x; 23.8265x over previous
//
#include <hip/hip_runtime.h>

#define B_  64
#define T_  2048
#define I_  128
#define H_  256
#define G4  1024   // 4*H
#define TC  128    // timestep chunk

#define HC  16     // W chunks register-resident (128 KB/block)
#define MC  9      // W chunks LDS-resident (144 KB/block)
#define SC  7      // W chunks streamed from L2 each step (112 KB/step)

typedef float    f32x4 __attribute__((ext_vector_type(4)));
typedef _Float16 f16x8 __attribute__((ext_vector_type(8)));
typedef _Float16 f16x2 __attribute__((ext_vector_type(2)));

__device__ __forceinline__ float dot2f(unsigned w, unsigned h, float acc) {
#if __has_builtin(__builtin_amdgcn_fdot2)
  return __builtin_amdgcn_fdot2(__builtin_bit_cast(f16x2, w),
                                __builtin_bit_cast(f16x2, h), acc, false);
#else
  f16x2 a = __builtin_bit_cast(f16x2, w), b = __builtin_bit_cast(f16x2, h);
  return acc + (float)a[0] * (float)b[0] + (float)a[1] * (float)b[1];
#endif
}

__device__ __forceinline__ unsigned short h16bits(float f) {
  return __builtin_bit_cast(unsigned short, (_Float16)f);
}
__device__ __forceinline__ float sigm(float x) { return 1.f / (1.f + __expf(-x)); }
__device__ __forceinline__ float tanh_fast(float x) { return 2.f / (1.f + __expf(-2.f * x)) - 1.f; }

// ---------------- prep kernels ----------------

// W_hh [1024][256] f32 -> wall[c4][row] uint4 of packed f16x2; chunk c4
// covers h-dims 8*c4 .. 8*c4+7.
__global__ void prep_w(const float* __restrict__ Whh, uint4* __restrict__ wall) {
  int idx = blockIdx.x * 256 + threadIdx.x;
  if (idx >= 32 * 1024) return;
  int c4 = idx >> 10, r = idx & 1023;
  unsigned q[4];
#pragma unroll
  for (int m = 0; m < 4; m++) {
    int kd = 4 * c4 + m;
    unsigned lo = h16bits(Whh[r * 256 + 2 * kd]);
    unsigned hi = h16bits(Whh[r * 256 + 2 * kd + 1]);
    q[m] = lo | (hi << 16);
  }
  wall[c4 * 1024 + r] = make_uint4(q[0], q[1], q[2], q[3]);
}

__global__ void prep_f16(const float* __restrict__ src, _Float16* __restrict__ dst, int n) {
  int i = blockIdx.x * 256 + threadIdx.x;
  if (i < n) dst[i] = (_Float16)src[i];
}

__global__ void prep_bias(const float* __restrict__ bi, const float* __restrict__ bh,
                          float* __restrict__ bias) {
  int i = blockIdx.x * 256 + threadIdx.x;
  if (i < G4) bias[i] = bi[i] + bh[i];
}

// ---------------- projection GEMM (f16 MFMA), xw stored f16 ----------------
template <int K, bool SRC_F32>
__global__ __launch_bounds__(256) void proj_kernel(const void* __restrict__ Asrc,
                                                   const _Float16* __restrict__ Wf,
                                                   const float* __restrict__ bias,
                                                   _Float16* __restrict__ xw, int t0) {
  const int m  = blockIdx.x;
  const int n0 = blockIdx.y * 64;
  const int tid = threadIdx.x;
  const int lane = tid & 63, wv = tid >> 6;

  __shared__ _Float16 As[64][40];
  __shared__ _Float16 Bs[64][40];

  f32x4 acc[4] = {f32x4{0,0,0,0}, f32x4{0,0,0,0}, f32x4{0,0,0,0}, f32x4{0,0,0,0}};

  const int r  = tid >> 2;
  const int kq = (tid & 3) * 8;
  const int r_g = m * 64 + r;
  const int b  = r_g >> 7;          // TC = 128
  const int tc = r_g & (TC - 1);
  long arow;
  if (SRC_F32) arow = (long)(b * T_ + t0 + tc) * K;
  else         arow = (long)r_g * K;

  for (int k0 = 0; k0 < K; k0 += 32) {
    if (SRC_F32) {
      const float* ap = (const float*)Asrc + arow + k0 + kq;
      float4 a0 = *(const float4*)ap;
      float4 a1 = *(const float4*)(ap + 4);
      _Float16* d = &As[r][kq];
      d[0] = (_Float16)a0.x; d[1] = (_Float16)a0.y; d[2] = (_Float16)a0.z; d[3] = (_Float16)a0.w;
      d[4] = (_Float16)a1.x; d[5] = (_Float16)a1.y; d[6] = (_Float16)a1.z; d[7] = (_Float16)a1.w;
    } else {
      const _Float16* ap = (const _Float16*)Asrc + arow + k0 + kq;
      *(uint4*)&As[r][kq] = *(const uint4*)ap;
    }
    *(uint4*)&Bs[r][kq] = *(const uint4*)(Wf + (long)(n0 + r) * K + k0 + kq);
    __syncthreads();

    f16x8 av = *(const f16x8*)&As[wv * 16 + (lane & 15)][(lane >> 4) * 8];
#pragma unroll
    for (int q = 0; q < 4; q++) {
      f16x8 bv = *(const f16x8*)&Bs[q * 16 + (lane & 15)][(lane >> 4) * 8];
      acc[q] = __builtin_amdgcn_mfma_f32_16x16x32_f16(av, bv, acc[q], 0, 0, 0);
    }
    __syncthreads();
  }

  const int row_in = wv * 16 + ((lane >> 4) << 2);
  const int col_in = lane & 15;
#pragma unroll
  for (int q = 0; q < 4; q++) {
#pragma unroll
    for (int i = 0; i < 4; i++) {
      int rr = m * 64 + row_in + i;
      int cc = n0 + q * 16 + col_in;
      xw[(long)rr * G4 + cc] = (_Float16)(acc[q][i] + bias[cc]);
    }
  }
}

// ---------------- recurrent scan ----------------
// One block (512 threads, 8 waves) per (batch, layer-job). Thread t:
// p=t&255, s=t>>8; owns rows r0=p+s*256, r1=r0+512 (s=0: i,g; s=1: f,o + c/h).
// W tiers: chunks 0..HC-1 pinned in registers (128 dw/thread; waves_per_eu(2,2)
// caps occupancy at 2/SIMD so the RA has no reason to spill); HC..HC+MC-1 in
// LDS; the last SC chunks streamed from the shared L2-resident array each step
// (opaque-pointer asm stops hoist-then-spill).
// A launch carries TWO independent jobs (layer0 chunk k, layer1 chunk k-1) on
// disjoint blocks -> layer pipelining with zero cross-block communication.

struct ScanJob {
  const _Float16* xw;      // [B*TC][1024] f16
  const uint4*    wall;    // [32][1024]
  const float*    mask;    // [B][256]
  float* hstate; float* cstate;
  _Float16* ychunk;        // layer0 output chunk (or null)
  float* out;              // layer1: d_out base (or null)
  float* hn; float* cn;    // last chunk only (or null)
  int t0; int valid;
};

#define C16(X) X(0) X(1) X(2) X(3) X(4) X(5) X(6) X(7) \
               X(8) X(9) X(10) X(11) X(12) X(13) X(14) X(15)

#define LOADW(i) \
  uint4 wA_##i = wall[(i) * 1024 + r0]; \
  uint4 wB_##i = wall[(i) * 1024 + r1];

#define PINW(i) \
  asm volatile("" : "+v"(wA_##i.x), "+v"(wA_##i.y), "+v"(wA_##i.z), "+v"(wA_##i.w), \
                    "+v"(wB_##i.x), "+v"(wB_##i.y), "+v"(wB_##i.z), "+v"(wB_##i.w));

#define DOTW(i) { uint4 hv = hs4[i]; \
  accA0 = dot2f(wA_##i.x, hv.x, accA0); accB0 = dot2f(wB_##i.x, hv.x, accB0); \
  accA1 = dot2f(wA_##i.y, hv.y, accA1); accB1 = dot2f(wB_##i.y, hv.y, accB1); \
  accA0 = dot2f(wA_##i.z, hv.z, accA0); accB0 = dot2f(wB_##i.z, hv.z, accB0); \
  accA1 = dot2f(wA_##i.w, hv.w, accA1); accB1 = dot2f(wB_##i.w, hv.w, accB1); }

__global__ __launch_bounds__(512)
__attribute__((amdgpu_waves_per_eu(2, 2)))
void scan_kernel(ScanJob j0, ScanJob j1) {
  ScanJob j = (blockIdx.x < B_) ? j0 : j1;
  if (!j.valid) return;
  const int b = blockIdx.x & (B_ - 1);
  const int t = threadIdx.x;
  const int p = t & 255, s = t >> 8;
  const int r0 = p + s * 256;
  const int r1 = r0 + 512;

  __shared__ uint4 wmid[MC * 1024];                    // 144 KB
  __shared__ __align__(16) unsigned short hsm[256];    // h packed f16
  __shared__ float pig[256];                           // sigm(i)*tanh(g)

  const uint4* wall = j.wall;

  // stage mid chunks into LDS (coalesced)
#pragma unroll
  for (int i = 0; i < MC * 2; i++)
    wmid[i * 512 + t] = wall[HC * 1024 + i * 512 + t];

  // head chunks into pinned registers (128 dwords/thread)
  C16(LOADW)
  C16(PINW)

  float c_reg = 0.f, h_reg = 0.f, mk = 0.f;
  if (s == 1) {
    c_reg = j.cstate[b * 256 + p];
    mk    = j.mask[b * 256 + p];
  }
  if (t < 128) {
    float h0v = j.hstate[b * 256 + 2 * t];
    float h1v = j.hstate[b * 256 + 2 * t + 1];
    ((unsigned*)hsm)[t] = (unsigned)h16bits(h0v) | ((unsigned)h16bits(h1v) << 16);
  }
  __syncthreads();

  const uint4* hs4 = (const uint4*)hsm;
  const _Float16* xwb = j.xw + (long)b * TC * G4;
  float xA = (float)xwb[r0], xB = (float)xwb[r1];
  float hm_prev = 0.f;

  for (int tc = 0; tc < TC; ++tc) {
    // prefetch next step's xw
    float nA = 0.f, nB = 0.f;
    if (tc + 1 < TC) {
      nA = (float)xwb[(long)(tc + 1) * G4 + r0];
      nB = (float)xwb[(long)(tc + 1) * G4 + r1];
    }

    // store previous step's output early (drain hides under the dots)
    if (s == 1 && tc > 0) {
      if (j.ychunk) j.ychunk[(b * TC + tc - 1) * H_ + p] = (_Float16)hm_prev;
      else          j.out[(long)(b * T_ + j.t0 + tc - 1) * H_ + p] = hm_prev;
    }

    float accA0 = xA, accA1 = 0.f, accB0 = xB, accB1 = 0.f;

    // ---- streamed tier first: issue loads early, L2-resident shared array
    {
      const uint4* wsp = wall + (HC + MC) * 1024;
      asm volatile("" : "+v"(wsp));   // opaque: no hoist across steps
#pragma unroll
      for (int m = 0; m < SC; m++) {
        uint4 hv = hs4[HC + MC + m];
        uint4 gA = wsp[m * 1024 + r0];
        uint4 gB = wsp[m * 1024 + r1];
        accA0 = dot2f(gA.x, hv.x, accA0); accB0 = dot2f(gB.x, hv.x, accB0);
        accA1 = dot2f(gA.y, hv.y, accA1); accB1 = dot2f(gB.y, hv.y, accB1);
        accA0 = dot2f(gA.z, hv.z, accA0); accB0 = dot2f(gB.z, hv.z, accB0);
        accA1 = dot2f(gA.w, hv.w, accA1); accB1 = dot2f(gB.w, hv.w, accB1);
      }
    }

    // ---- register tier
    C16(DOTW)

    // ---- LDS tier
#pragma unroll
    for (int m = 0; m < MC; m++) {
      uint4 hv = hs4[HC + m];
      uint4 tA = wmid[m * 1024 + r0];
      uint4 tB = wmid[m * 1024 + r1];
      accA0 = dot2f(tA.x, hv.x, accA0); accB0 = dot2f(tB.x, hv.x, accB0);
      accA1 = dot2f(tA.y, hv.y, accA1); accB1 = dot2f(tB.y, hv.y, accB1);
      accA0 = dot2f(tA.z, hv.z, accA0); accB0 = dot2f(tB.z, hv.z, accB0);
      accA1 = dot2f(tA.w, hv.w, accA1); accB1 = dot2f(tB.w, hv.w, accB1);
    }

    float aF = accA0 + accA1;   // s=0: pre_i ; s=1: pre_f
    float bF = accB0 + accB1;   // s=0: pre_g ; s=1: pre_o

    if (s == 0) pig[p] = sigm(aF) * tanh_fast(bF);
    __syncthreads();
    if (s == 1) {
      c_reg = sigm(aF) * c_reg + pig[p];
      h_reg = sigm(bF) * tanh_fast(c_reg);
      hsm[p] = h16bits(h_reg);
      hm_prev = h_reg * mk;
    }
    xA = nA; xB = nB;
    __syncthreads();
  }

  if (s == 1) {
    if (j.ychunk) j.ychunk[(b * TC + TC - 1) * H_ + p] = (_Float16)hm_prev;
    else          j.out[(long)(b * T_ + j.t0 + TC - 1) * H_ + p] = hm_prev;
    j.hstate[b * 256 + p] = h_reg;
    j.cstate[b * 256 + p] = c_reg;
    if (j.hn) { j.hn[b * 256 + p] = h_reg; j.cn[b * 256 + p] = c_reg; }
  }
}

// ---------------- host launch ----------------
extern "C" void kernel_launch(void* const* d_in, const int* in_sizes, int n_in,
                              void* d_out, int out_size, void* d_ws, size_t ws_size,
                              hipStream_t stream) {
  const float* x     = (const float*)d_in[0];
  const float* Wih0  = (const float*)d_in[1];
  const float* Whh0  = (const float*)d_in[2];
  const float* bih0  = (const float*)d_in[3];
  const float* bhh0  = (const float*)d_in[4];
  const float* mask0 = (const float*)d_in[5];
  const float* Wih1  = (const float*)d_in[6];
  const float* Whh1  = (const float*)d_in[7];
  const float* bih1  = (const float*)d_in[8];
  const float* bhh1  = (const float*)d_in[9];
  const float* mask1 = (const float*)d_in[10];

  float* out = (float*)d_out;
  float* hn  = out + (long)B_ * T_ * H_;   // [2][64][256]
  float* cn  = hn + 2 * B_ * H_;

  char* w = (char*)d_ws;
  uint4*    wall0  = (uint4*)w;      w += 512 << 10;   // [32][1024] uint4
  uint4*    wall1  = (uint4*)w;      w += 512 << 10;
  _Float16* wf0    = (_Float16*)w;   w += 256 << 10;
  _Float16* wf1    = (_Float16*)w;   w += 512 << 10;
  float*    bias0  = (float*)w;      w += 4 << 10;
  float*    bias1  = (float*)w;      w += 4 << 10;
  float*    h0s    = (float*)w;      w += 64 << 10;
  float*    c0s    = (float*)w;      w += 64 << 10;
  float*    h1s    = (float*)w;      w += 64 << 10;
  float*    c1s    = (float*)w;      w += 64 << 10;
  _Float16* xw0    = (_Float16*)w;   w += (long)B_ * TC * G4 * 2;   // 16 MB
  _Float16* xw1    = (_Float16*)w;   w += (long)B_ * TC * G4 * 2;   // 16 MB
  _Float16* ybuf   = (_Float16*)w;   w += (long)B_ * TC * H_ * 2;   // 4 MB

  hipMemsetAsync(h0s, 0, 4 * (64 << 10), stream);

  prep_w<<<128, 256, 0, stream>>>(Whh0, wall0);
  prep_w<<<128, 256, 0, stream>>>(Whh1, wall1);
  prep_f16<<<512, 256, 0, stream>>>(Wih0, wf0, G4 * I_);
  prep_f16<<<1024, 256, 0, stream>>>(Wih1, wf1, G4 * H_);
  prep_bias<<<4, 256, 0, stream>>>(bih0, bhh0, bias0);
  prep_bias<<<4, 256, 0, stream>>>(bih1, bhh1, bias1);

  const int nchunk = T_ / TC;  // 16
  for (int k = 0; k <= nchunk; k++) {
    if (k < nchunk) {
      proj_kernel<I_, true><<<dim3(B_ * TC / 64, G4 / 64), 256, 0, stream>>>(
          x, wf0, bias0, xw0, k * TC);
    }
    ScanJob j0, j1;
    // layer 0, chunk k
    j0.xw = xw0; j0.wall = wall0; j0.mask = mask0;
    j0.hstate = h0s; j0.cstate = c0s;
    j0.ychunk = ybuf; j0.out = nullptr;
    j0.hn = (k == nchunk - 1) ? hn : nullptr;
    j0.cn = (k == nchunk - 1) ? cn : nullptr;
    j0.t0 = k * TC; j0.valid = (k < nchunk);
    // layer 1, chunk k-1
    j1.xw = xw1; j1.wall = wall1; j1.mask = mask1;
    j1.hstate = h1s; j1.cstate = c1s;
    j1.ychunk = nullptr; j1.out = out;
    j1.hn = (k == nchunk) ? hn + B_ * H_ : nullptr;
    j1.cn = (k == nchunk) ? cn + B_ * H_ : nullptr;
    j1.t0 = (k - 1) * TC; j1.valid = (k >= 1);

    scan_kernel<<<2 * B_, 512, 0, stream>>>(j0, j1);

    if (k < nchunk) {
      proj_kernel<H_, false><<<dim3(B_ * TC / 64, G4 / 64), 256, 0, stream>>>(
          ybuf, wf1, bias1, xw1, k * TC);
    }
  }
}